// Round 6
// baseline (670.926 us; speedup 1.0000x reference)
//
#include <hip/hip_runtime.h>
#include <stdint.h>

typedef float  f32x4  __attribute__((ext_vector_type(4)));
typedef short  bf16x8 __attribute__((ext_vector_type(8)));
typedef unsigned short u16;
typedef unsigned short u16x8 __attribute__((ext_vector_type(8)));

// async global->LDS, 16B per lane; LDS dest is wave-uniform base + lane*16
#define GLD16(gsrc, ldst) \
  __builtin_amdgcn_global_load_lds((const __attribute__((address_space(1))) uint32_t*)(gsrc), \
                                   (__attribute__((address_space(3))) uint32_t*)(ldst), 16, 0, 0)

static __device__ __forceinline__ u16 f2bf(float f) {
  union { float f; uint32_t u; } v; v.f = f;
  uint32_t r = (v.u + 0x7FFFu + ((v.u >> 16) & 1u)) >> 16;  // RTNE
  return (u16)r;
}

// ---------------- P0: 4x4 matrices + alpha -> consts[80], plus folded bias [2048] ----------------
__global__ void k_prepbias(const float* __restrict__ HpreA_l, const float* __restrict__ HpreH_l,
                           const float* __restrict__ HresA_l, const float* __restrict__ HpostA_l,
                           const float* __restrict__ scalesA,
                           const float* __restrict__ HresH_l, const float* __restrict__ HpostH_l,
                           const float* __restrict__ scalesH,
                           const float* __restrict__ crossmix, float* __restrict__ consts,
                           const float* __restrict__ bA, const float* __restrict__ bH,
                           float* __restrict__ bias) {
  __shared__ float sc[80];
  if (threadIdx.x == 0) {
    float alpha = 1.0f / (1.0f + expf(-crossmix[0]));
    float Pa[16], Ph[16], SA[16], SH[16], QA[16], QH[16];
    const float* Ls[4] = {HpreA_l, HpreH_l, HpostA_l, HpostH_l};
    float* Os[4] = {Pa, Ph, QA, QH};
    for (int m = 0; m < 4; ++m) {
      for (int r = 0; r < 4; ++r) {
        float mx = Ls[m][r*4+0];
        for (int c = 1; c < 4; ++c) mx = fmaxf(mx, Ls[m][r*4+c]);
        float s = 0.f;
        for (int c = 0; c < 4; ++c) { float e = expf(Ls[m][r*4+c] - mx); Os[m][r*4+c] = e; s += e; }
        for (int c = 0; c < 4; ++c) Os[m][r*4+c] /= s;
      }
    }
    const float* Lr[2] = {HresA_l, HresH_l};
    float* Or[2] = {SA, SH};
    for (int m = 0; m < 2; ++m) {
      float mx = Lr[m][0];
      for (int i = 1; i < 16; ++i) mx = fmaxf(mx, Lr[m][i]);
      for (int i = 0; i < 16; ++i) Or[m][i] = expf(Lr[m][i] - mx);
      for (int it = 0; it < 20; ++it) {
        for (int r = 0; r < 4; ++r) {
          float s = 1e-8f;
          for (int c = 0; c < 4; ++c) s += Or[m][r*4+c];
          for (int c = 0; c < 4; ++c) Or[m][r*4+c] /= s;
        }
        for (int c = 0; c < 4; ++c) {
          float s = 1e-8f;
          for (int r = 0; r < 4; ++r) s += Or[m][r*4+c];
          for (int r = 0; r < 4; ++r) Or[m][r*4+c] /= s;
        }
      }
    }
    for (int i = 0; i < 16; ++i) sc[i]      = Pa[i];
    for (int i = 0; i < 16; ++i) sc[16 + i] = Ph[i];
    for (int i = 0; i < 16; ++i) sc[32 + i] = alpha * SA[i] + (1.0f - alpha) * SH[i];
    for (int t = 0; t < 4; ++t)
      for (int s = 0; s < 4; ++s) {
        sc[48 + t*4 + s] = alpha * scalesA[t] * QA[t*4 + s];
        sc[64 + t*4 + s] = (1.0f - alpha) * scalesH[t] * QH[t*4 + s];
      }
    for (int i = 0; i < 80; ++i) consts[i] = sc[i];
  }
  __syncthreads();
  #pragma unroll
  for (int k = 0; k < 8; ++k) {
    int j = k*256 + threadIdx.x;     // 0..2047
    int t = j >> 9, d = j & 511;
    float acc = 0.f;
    for (int s = 0; s < 4; ++s)
      acc += sc[48 + t*4 + s] * bA[s*512 + d] + sc[64 + t*4 + s] * bH[s*512 + d];
    bias[j] = acc;
  }
}

// ---------------- P1a: fold 4x4 mixes into weights; f32 temp [4096][2048] ----------------
__global__ __launch_bounds__(256) void k_fold(const float* __restrict__ Wa,
                                              const float* __restrict__ Wh,
                                              const float* __restrict__ consts,
                                              float* __restrict__ temp) {
  int bid  = blockIdx.x;                 // 0..2047
  int da   = bid >> 2;                   // 0..511
  int half = (bid >> 1) & 1;
  int j4   = (bid & 1) * 256 + threadIdx.x;  // 0..511  (output col / 4)
  int t    = j4 >> 7;
  int dcol = (j4 & 127) * 4;
  const float* W  = half ? Wh : Wa;
  const float* Hp = consts + (half ? 16 : 0);
  const float* C  = consts + (half ? 64 : 48);
  float c_t[4];
  for (int s = 0; s < 4; ++s) c_t[s] = C[t*4 + s];
  f32x4 acc[4];
  for (int p = 0; p < 4; ++p) for (int e = 0; e < 4; ++e) acc[p][e] = 0.f;
  #pragma unroll
  for (int u = 0; u < 4; ++u) {
    float hp[4];
    for (int p = 0; p < 4; ++p) hp[p] = Hp[p*4 + u];
    #pragma unroll
    for (int s = 0; s < 4; ++s) {
      f32x4 wv = *(const f32x4*)&W[(size_t)(u*512 + da) * 2048 + s*512 + dcol];
      float cs = c_t[s];
      for (int p = 0; p < 4; ++p) acc[p] += (hp[p] * cs) * wv;
    }
  }
  if (half) {
    int e = da - dcol;
    if (e >= 0 && e < 4)
      for (int p = 0; p < 4; ++p) acc[p][e] += consts[32 + p*4 + t];
  }
  for (int p = 0; p < 4; ++p)
    *(f32x4*)&temp[(size_t)(half*2048 + p*512 + da) * 2048 + j4*4] = acc[p];
}

// ---------------- P1T: transpose temp [4096][2048] f32 -> Wc_t [2048][4096] bf16 ----------------
__global__ __launch_bounds__(256) void k_transpose(const float* __restrict__ temp,
                                                   u16* __restrict__ Bt) {
  __shared__ float tile[64][65];
  int r0 = blockIdx.x * 64;   // rows of temp (0..4095)
  int c0 = blockIdx.y * 64;   // cols of temp (0..2047)
  int tid = threadIdx.x;
  int lr = tid >> 4;          // 0..15
  int lc = (tid & 15) * 4;    // 0..60
  #pragma unroll
  for (int i = 0; i < 4; ++i) {
    int row = lr + i * 16;
    f32x4 v = *(const f32x4*)&temp[(size_t)(r0 + row) * 2048 + c0 + lc];
    tile[row][lc+0] = v[0]; tile[row][lc+1] = v[1];
    tile[row][lc+2] = v[2]; tile[row][lc+3] = v[3];
  }
  __syncthreads();
  #pragma unroll
  for (int k = 0; k < 4; ++k) {
    int jj = lr + k * 16;     // col of temp = row of Bt
    ushort4 o;
    o.x = f2bf(tile[lc+0][jj]); o.y = f2bf(tile[lc+1][jj]);
    o.z = f2bf(tile[lc+2][jj]); o.w = f2bf(tile[lc+3][jj]);
    *(ushort4*)&Bt[(size_t)(c0 + jj) * 4096 + r0 + lc] = o;
  }
}

// ---------------- P2: per-row LN + materialize A bf16 [16384][4096] ----------------
__global__ __launch_bounds__(256) void k_rowprep(const float* __restrict__ x,
                                                 const float* __restrict__ gamma,
                                                 const float* __restrict__ beta,
                                                 u16* __restrict__ A) {
  int wid = (blockIdx.x * 256 + threadIdx.x) >> 6;   // 0..16383 (row)
  int l = threadIdx.x & 63;
  const float* row = x + (size_t)wid * 2048;
  f32x4 v[8];
  float s1 = 0.f, s2 = 0.f;
  #pragma unroll
  for (int j = 0; j < 8; ++j) {
    v[j] = *(const f32x4*)&row[j*256 + l*4];
    #pragma unroll
    for (int e = 0; e < 4; ++e) { s1 += v[j][e]; s2 += v[j][e]*v[j][e]; }
  }
  #pragma unroll
  for (int off = 32; off; off >>= 1) {
    s1 += __shfl_down(s1, off, 64);
    s2 += __shfl_down(s2, off, 64);
  }
  s1 = __shfl(s1, 0, 64);
  s2 = __shfl(s2, 0, 64);
  float mu   = s1 * (1.0f/2048.0f);
  float var  = s2 * (1.0f/2048.0f) - mu*mu;
  float rstd = rsqrtf(var + 1e-5f);
  u16* An = A + (size_t)wid * 4096;
  #pragma unroll
  for (int j = 0; j < 8; ++j) {
    f32x4 g = *(const f32x4*)&gamma[j*256 + l*4];
    f32x4 b = *(const f32x4*)&beta[j*256 + l*4];
    ushort4 pn, pr;
    pn.x = f2bf((v[j][0]-mu)*rstd*g[0] + b[0]);
    pn.y = f2bf((v[j][1]-mu)*rstd*g[1] + b[1]);
    pn.z = f2bf((v[j][2]-mu)*rstd*g[2] + b[2]);
    pn.w = f2bf((v[j][3]-mu)*rstd*g[3] + b[3]);
    pr.x = f2bf(v[j][0]); pr.y = f2bf(v[j][1]);
    pr.z = f2bf(v[j][2]); pr.w = f2bf(v[j][3]);
    *(ushort4*)&An[j*256 + l*4]        = pn;   // normed half (K 0..2047)
    *(ushort4*)&An[2048 + j*256 + l*4] = pr;   // raw half    (K 2048..4095)
  }
}

// ---------------- GEMM: 256x256 tile, BK=64, 4-phase/K-tile, row-split staging (R6) ----------------
// out[16384][2048] = A[16384][4096] @ Bt^T + bias.  Bt is [2048][4096] (N-major).
// 512 threads = 8 waves (2 M x 4 N), wave tile 128x64, 16x16x32 bf16 MFMA.
// LDS: per operand 2 dbuf x [256 rows][64 k] bf16 (32 KiB) = 64 KiB; total 128 KiB.
//
// R6 change (from R5 post-mortem): staging unit is a ROW-half [128 rows][64 k] = full
// 128-B lines (R5's K-half unit was 64 B/row -> 2x L1/TA transactions; conflicts were 0
// but time unchanged -> request rate, not banks, was the suspect). Swizzle: 16-B chunk
// c (0..7) within each 128-B row XORed with (row&7) — one full line per 8 lanes on the
// source side (coalescing preserved: permutation stays within the line), conflict-free
// ds_read (8-lane service group covers 8 distinct 4-bank groups). Same involution on
// the pre-swizzled global source and the frag-read address.
//
// Schedule per K-tile (4 phases, reads from cur = kt&1; tile kt+2 staged into cur's
// DEAD regions): ph0 [rd B.ks0 + A.mq0 (12)] ph1 [rd B.ks1 (4)] ph2 [rd A.mq1 (8);
// STAGE B(kt+2) — cur-B dead after ph1's bar] ph3 [STAGE A(kt+2) — cur-A dead after
// ph2's bar; VM(8)]. Ledger: tile t staged during t-2, guard vmcnt(8) once per tile
// leaves exactly tile kt+2's 8 loads in flight => tile kt+1 landed; lead 5-6 phases.
// Tail: kt=62 stages nothing + VM(0); kt=63 plain. Prologue: tiles 0,1 (16 loads), VM(8).

#define STAGE_A(ktt, h, dt) { const char* g_ = gA + (size_t)(h)*1048576 + (size_t)(ktt)*128; \
  char* s_ = lA + (dt)*32768 + (h)*16384; GLD16(g_ + go0, s_ + lo0); GLD16(g_ + go1, s_ + lo1); }
#define STAGE_B(ktt, h, dt) { const char* g_ = gB + (size_t)(h)*1048576 + (size_t)(ktt)*128; \
  char* s_ = lB + (dt)*32768 + (h)*16384; GLD16(g_ + go0, s_ + lo0); GLD16(g_ + go1, s_ + lo1); }
#define VM(n) { asm volatile("s_waitcnt vmcnt(" #n ")" ::: "memory"); __builtin_amdgcn_sched_barrier(0); }
#define BAR() __builtin_amdgcn_s_barrier()

#define RD4(F, BASE, X) { _Pragma("unroll") for (int i_ = 0; i_ < 4; ++i_) \
  F[i_] = *(const bf16x8*)((BASE) + i_*2048 + (X)); }

#define MFMA16(O, AF, BF) { __builtin_amdgcn_s_setprio(1); \
  _Pragma("unroll") for (int mi_ = 0; mi_ < 4; ++mi_) \
    _Pragma("unroll") for (int ni_ = 0; ni_ < 4; ++ni_) \
      acc[(O)+mi_][ni_] = __builtin_amdgcn_mfma_f32_16x16x32_bf16(AF[mi_], BF[ni_], acc[(O)+mi_][ni_], 0, 0, 0); \
  __builtin_amdgcn_s_setprio(0); }

// one K-tile: 4 phases, each {ds_read || stage -> BAR -> 16 MFMA -> BAR}
#define KBODY(KT, CUR, DOSTAGE, ...) { \
  int co_ = (CUR) * 32768; \
  const char* pa_ = lA + co_ + abase; \
  const char* pb_ = lB + co_ + bbase; \
  bf16x8 Af0[4], Af1[4], Bf0[4], Bf1[4]; \
  /* ph0: quadrant mq0 x ks0 */ \
  RD4(Bf0, pb_, xa); RD4(Af0, pa_, xa); RD4(Af1, pa_, xa ^ 64); \
  BAR(); MFMA16(0, Af0, Bf0); BAR(); \
  /* ph1: mq0 x ks1 */ \
  RD4(Bf1, pb_, xa ^ 64); \
  BAR(); MFMA16(0, Af1, Bf1); BAR(); \
  /* ph2: mq1 x ks0 ; stage B(kt+2) into cur (B region dead after ph1 bar) */ \
  RD4(Af0, pa_ + 8192, xa); RD4(Af1, pa_ + 8192, xa ^ 64); \
  if (DOSTAGE) { STAGE_B((KT)+2, 0, (CUR)); STAGE_B((KT)+2, 1, (CUR)); } \
  BAR(); MFMA16(4, Af0, Bf0); BAR(); \
  /* ph3: mq1 x ks1 ; stage A(kt+2) into cur (A region dead after ph2 bar) */ \
  if (DOSTAGE) { STAGE_A((KT)+2, 0, (CUR)); STAGE_A((KT)+2, 1, (CUR)); } \
  BAR(); MFMA16(4, Af1, Bf1); __VA_ARGS__; BAR(); \
}

__global__ __launch_bounds__(512, 2) void k_gemm8(const u16* __restrict__ A,
                                                  const u16* __restrict__ B,
                                                  const float* __restrict__ bias,
                                                  float* __restrict__ out) {
  __shared__ __align__(16) u16 ldsA[2*256*64];
  __shared__ __align__(16) u16 ldsB[2*256*64];
  int bid = blockIdx.x;                       // 0..511 ; 512 % 8 == 0 -> simple XCD swizzle ok
  int swz = (bid & 7) * 64 + (bid >> 3);
  int mt = swz >> 3, nt = swz & 7;
  int m0 = mt * 256, n0 = nt * 256;
  int tid = threadIdx.x;
  int w = tid >> 6, l = tid & 63;
  int wr = w >> 2, wc = w & 3;                // 2 x 4 waves
  int lr = l & 15, lk = l >> 4;
  const char* gA = (const char*)A + (size_t)m0 * 8192;   // row stride 4096*2B
  const char* gB = (const char*)B + (size_t)n0 * 8192;
  char* lA = (char*)ldsA;
  char* lB = (char*)ldsB;

  // staging: half-tile [128 rows][128 B]; thread covers chunk q = j*512+tid
  // (row = q>>3, c = q&7); source pre-swizzled c ^= row&7 (stays within the 128-B line)
  size_t go0 = (size_t)(tid >> 3) * 8192 + (size_t)(((tid & 7) ^ ((tid >> 3) & 7)) << 4);
  size_t go1 = go0 + (size_t)64 * 8192;                  // rows 64..127 of the half
  int lo0 = w * 1024, lo1 = 8192 + w * 1024;             // wave-uniform LDS bases (+h*16384+d*32768)

  // frag reads: row*128 + ((chunk ^ (row&7))<<4); row&7 == lr&7 for all frag rows
  int xa = (lk ^ (lr & 7)) << 4;                         // ks0 chunk lk ; ks1 = xa^64
  int abase = (wr*128 + lr) * 128;                       // + mq*8192 + mi*2048
  int bbase = (wc*64  + lr) * 128;                       // + ni*2048

  f32x4 acc[8][4];
  #pragma unroll
  for (int mi = 0; mi < 8; ++mi)
    #pragma unroll
    for (int ni = 0; ni < 4; ++ni)
      #pragma unroll
      for (int e = 0; e < 4; ++e) acc[mi][ni][e] = 0.f;

  // prologue: tile0 -> dbuf0, tile1 -> dbuf1 (16 loads); VM(8) = tile0 landed
  STAGE_A(0, 0, 0); STAGE_A(0, 1, 0); STAGE_B(0, 0, 0); STAGE_B(0, 1, 0);
  STAGE_A(1, 0, 1); STAGE_A(1, 1, 1); STAGE_B(1, 0, 1); STAGE_B(1, 1, 1);
  VM(8);
  BAR();

  for (int kt = 0; kt < 62; ++kt) {
    KBODY(kt, kt & 1, 1, VM(8));
  }
  KBODY(62, 0, 0, VM(0));
  KBODY(63, 1, 0, );

  // epilogue: C = acc + bias
  #pragma unroll
  for (int ni = 0; ni < 4; ++ni) {
    int col = n0 + wc*64 + ni*16 + lr;
    float bc = bias[col];
    #pragma unroll
    for (int mi = 0; mi < 8; ++mi) {
      int row = m0 + wr*128 + mi*16 + lk*4;
      #pragma unroll
      for (int e = 0; e < 4; ++e)
        out[(size_t)(row + e) * 2048 + col] = acc[mi][ni][e] + bc;
    }
  }
}

// ---------------- emergency: encode ws_size(MB) into d_out so failure is diagnosable ----------------
__global__ void k_report(float* out, float v) {
  out[blockIdx.x * 256 + threadIdx.x] = v;
}

extern "C" void kernel_launch(void* const* d_in, const int* in_sizes, int n_in,
                              void* d_out, int out_size, void* d_ws, size_t ws_size,
                              hipStream_t stream) {
  (void)in_sizes; (void)n_in; (void)out_size;
  const float* x       = (const float*)d_in[0];
  const float* gamma   = (const float*)d_in[1];
  const float* beta    = (const float*)d_in[2];
  const float* Wa      = (const float*)d_in[3];
  const float* ba      = (const float*)d_in[4];
  const float* Wh      = (const float*)d_in[5];
  const float* bh      = (const float*)d_in[6];
  const float* HpreA   = (const float*)d_in[7];
  const float* HpreH   = (const float*)d_in[8];
  const float* HresA   = (const float*)d_in[9];
  const float* HpostA  = (const float*)d_in[10];
  const float* scalesA = (const float*)d_in[11];
  const float* HresH   = (const float*)d_in[12];
  const float* HpostH  = (const float*)d_in[13];
  const float* scalesH = (const float*)d_in[14];
  const float* cm      = (const float*)d_in[15];
  float* out = (float*)d_out;

  const size_t OFF_CONST = 0;
  const size_t OFF_BIAS  = 4096;
  const size_t OFF_B     = (size_t)1 << 20;    // Wc_t bf16 [2048][4096] = 16 MiB
  const size_t OFF_A     = (size_t)17 << 20;   // A bf16 [16384][4096] = 128 MiB (first 32MiB doubles as f32 fold temp)
  const size_t NEED      = OFF_A + ((size_t)128 << 20);

  if (ws_size < NEED) {
    k_report<<<4, 256, 0, stream>>>(out, (float)(ws_size >> 20));
    return;
  }

  float* consts = (float*)((char*)d_ws + OFF_CONST);
  float* bias   = (float*)((char*)d_ws + OFF_BIAS);
  u16*   Bt     = (u16*)((char*)d_ws + OFF_B);
  u16*   Am     = (u16*)((char*)d_ws + OFF_A);
  float* temp   = (float*)((char*)d_ws + OFF_A);   // reused before Am is written

  k_prepbias<<<1, 256, 0, stream>>>(HpreA, HpreH, HresA, HpostA, scalesA,
                                    HresH, HpostH, scalesH, cm, consts, ba, bh, bias);
  k_fold<<<2048, 256, 0, stream>>>(Wa, Wh, consts, temp);
  k_transpose<<<dim3(64, 32), 256, 0, stream>>>(temp, Bt);
  k_rowprep<<<4096, 256, 0, stream>>>(x, gamma, beta, Am);   // overwrites temp area — must follow k_transpose
  k_gemm8<<<512, 512, 0, stream>>>(Am, Bt, bias, out);
}